// Round 10
// baseline (101.723 us; speedup 1.0000x reference)
//
#include <hip/hip_runtime.h>
#include <hip/hip_bf16.h>

typedef short bf16x8 __attribute__((ext_vector_type(8)));
typedef float f32x16 __attribute__((ext_vector_type(16)));

#define NCOL  32
#define KS1   112             // f1 k-steps (K=1792, 16 per step, 4 s per step)
#define KS2   12              // f2 k-steps (K=192)
#define ESTR  264             // E row stride bytes (32 cols * 8B + 8 pad: bank-spread)

#define WP_OFF   0            // short [112][3][64][8] = 344064 B
#define W2P_OFF  344064       // short [12][3][64][8]  = 36864 B

#define MET_OFF  10824        // E region 41*264 = 10824; meta uint2[464] = 3712
#define SUM_OFF  14544        // f32 [192][32] = 24576
#define LDS_BYTES 39120

__device__ __forceinline__ unsigned short f2bf(float f) {
    union { float f; unsigned u; } v; v.f = f;
    unsigned r = v.u + 0x7FFFu + ((v.u >> 16) & 1u);
    return (unsigned short)(r >> 16);
}
__device__ __forceinline__ float bfl(unsigned u) {
    union { unsigned q; float f; } v; v.q = u << 16; return v.f;
}
__device__ __forceinline__ float bfh(unsigned u) {
    union { unsigned q; float f; } v; v.q = u & 0xffff0000u; return v.f;
}
__device__ __forceinline__ unsigned pk2(float a, float b) {
    __hip_bfloat162 h = __float22bfloat162_rn(make_float2(a, b));
    unsigned u; __builtin_memcpy(&u, &h, 4); return u;
}
__device__ __forceinline__ bf16x8 asbf(uint4 v) {
    union { uint4 u; bf16x8 b; } z; z.u = v; return z.b;
}
__device__ __forceinline__ f32x16 zero16() {
    f32x16 z;
#pragma unroll
    for (int i = 0; i < 16; ++i) z[i] = 0.f;
    return z;
}

// prep: A-fragment layout for mfma_32x32x16: Wp[ks][mt][lane][8 shorts],
// lane: row-in-tile = lane&31, k = (lane>>5)*8 + v. Row r = o*4+p*2+reim
// (rows 80-83 = pbc C rows, 84-95 zero). k→(s = k>>2; t = k&3: i=t&1 pol,
// cc=t>>1 re/im; plane j = i^p). Value formula validated r7-r9.
__global__ void prep_kernel(const float* __restrict__ W1,
                            const float* __restrict__ W2,
                            const float* __restrict__ pbcC,
                            unsigned short* __restrict__ Wp,
                            unsigned short* __restrict__ W2p, int S) {
    int idx = blockIdx.x * 256 + threadIdx.x;
    const int N1 = KS1 * 3 * 64 * 2;   // 43008
    const int N2 = KS2 * 3 * 64 * 2;   // 4608
    if (idx < N1) {
        int ks = idx / 384, rem = idx - ks * 384;
        int mt = rem >> 7; rem &= 127;
        int lane = rem >> 1, jh = rem & 1;
        int row = mt * 32 + (lane & 31);
        int kg  = ks * 16 + (lane >> 5) * 8 + jh * 4;
        int s   = kg >> 2;
        float2 wj0 = make_float2(0.f, 0.f), wj1 = make_float2(0.f, 0.f);
        int p = 0, r = 0;
        if (s < S) {
            if (row < 80) {
                int o = row >> 2; p = (row >> 1) & 1; r = row & 1;
                wj0 = ((const float2*)W1)[(size_t)(o * 2 + 0) * S + s];
                wj1 = ((const float2*)W1)[(size_t)(o * 2 + 1) * S + s];
            } else if (row < 84) {
                p = (row >> 1) & 1; r = row & 1;
                wj0 = ((const float2*)pbcC)[s];
            }
        }
        ushort4 h; unsigned short us[4];
#pragma unroll
        for (int t = 0; t < 4; ++t) {
            int i = t & 1, cc = t >> 1, j2 = i ^ p;
            float2 w = j2 ? wj1 : wj0;
            float v = (cc == 0) ? (r ? w.y : w.x) : (r ? w.x : -w.y);
            us[t] = f2bf(v);
        }
        h.x = us[0]; h.y = us[1]; h.z = us[2]; h.w = us[3];
        ((ushort4*)Wp)[idx] = h;
        return;
    }
    idx -= N1;
    if (idx < N2) {
        int ks = idx / 384, rem = idx - ks * 384;
        int mt = rem >> 7; rem &= 127;
        int lane = rem >> 1, jh = rem & 1;
        int row = mt * 32 + (lane & 31);
        int kg  = ks * 16 + (lane >> 5) * 8 + jh * 4;
        int m   = kg >> 2;
        float2 wj0 = make_float2(0.f, 0.f), wj1 = make_float2(0.f, 0.f);
        int p = 0, r = 0;
        if (m < 41 && row < 80) {
            int o = row >> 2; p = (row >> 1) & 1; r = row & 1;
            wj0 = ((const float2*)W2)[(o * 2 + 0) * 41 + m];
            wj1 = ((const float2*)W2)[(o * 2 + 1) * 41 + m];
        }
        ushort4 h; unsigned short us[4];
#pragma unroll
        for (int t = 0; t < 4; ++t) {
            int i = t & 1, cc = t >> 1, j2 = i ^ p;
            float2 w = j2 ? wj1 : wj0;
            float v = (cc == 0) ? (r ? w.y : w.x) : (r ? w.x : -w.y);
            us[t] = f2bf(v);
        }
        h.x = us[0]; h.y = us[1]; h.z = us[2]; h.w = us[3];
        ((ushort4*)W2p)[idx] = h;
    }
}

// Fused: 32 cols/block, 4 waves = K-quarters. Software-pipelined barrier-free
// K-loop (meta 2 ahead in regs, E 1 ahead). f2 after f1 reduction (acc reuse).
__global__ __launch_bounds__(256, 3) void eqsonn_kernel(
    const float* __restrict__ x, const float* __restrict__ task,
    const unsigned short* __restrict__ Wp,  // short [112][3][64][8]
    const unsigned short* __restrict__ W2p, // short [12][3][64][8]
    const int* __restrict__ m_idx, const int* __restrict__ n_idx,
    const float* __restrict__ b1, const float* __restrict__ b2,
    float* __restrict__ out, int B, int S)
{
    __shared__ alignas(16) char ldsb[LDS_BYTES];
    const int tid  = threadIdx.x;
    const int lane = tid & 63;
    const int w    = __builtin_amdgcn_readfirstlane(tid >> 6);
    const int col  = lane & 31;
    const int kha  = lane >> 5;
    const int b0   = blockIdx.x * NCOL;

    // ---- stage E bf16: row k at k*264, col*8 ----
    for (int e = tid; e < 41 * NCOL; e += 256) {
        int bb = e / 41, k = e - bb * 41;
        int bs = b0 + bb; if (bs > B - 1) bs = B - 1;
        float4 v = ((const float4*)x)[(size_t)bs * 41 + k];
        ushort4 h;
        h.x = f2bf(v.x); h.y = f2bf(v.y); h.z = f2bf(v.z); h.w = f2bf(v.w);
        *(ushort4*)(ldsb + k * ESTR + bb * 8) = h;
    }
    // ---- stage meta byte-offsets, zero-padded to 464 ----
    for (int i = tid; i < 464; i += 256) {
        int m = 0, n = 0;
        if (i < S) { m = m_idx[i]; n = n_idx[i]; }
        unsigned offM = (unsigned)((20 + m) * ESTR);
        unsigned offB = (unsigned)((20 + m + n) * ESTR);
        unsigned offN = (unsigned)((20 + n) * ESTR);
        *(uint2*)(ldsb + MET_OFF + i * 8) = make_uint2(offM | (offB << 16), offN);
    }
    __syncthreads();

    const char* Ebase = ldsb + col * 8;
    auto ldM4 = [&](int ks) -> uint4 {
        return *(const uint4*)(ldsb + MET_OFF + (ks * 4 + kha * 2) * 8);
    };
    auto ldE = [&](unsigned off) -> uint2 {
        return *(const uint2*)(Ebase + off);
    };
    auto fbuild = [&](uint2 em, uint2 eq, uint2 en, unsigned& lo, unsigned& hi) {
        float m0r = bfl(em.x), m0i = bfh(em.x), m1r = bfl(em.y), m1i = bfh(em.y);
        float q0r = bfl(eq.x), q0i = bfh(eq.x), q1r = bfl(eq.y), q1i = bfh(eq.y);
        float n0r = bfl(en.x), n0i = bfh(en.x), n1r = bfl(en.y), n1i = bfh(en.y);
        float sr = m0r * q0r + m0i * q0i + m1r * q1r + m1i * q1i;
        float si = m0i * q0r - m0r * q0i + m1i * q1r - m1r * q1i;
        float F0r = sr * n0r - si * n0i, F0i = sr * n0i + si * n0r;
        float F1r = sr * n1r - si * n1i, F1i = sr * n1i + si * n1r;
        lo = pk2(F0r, F1r); hi = pk2(F0i, F1i);
    };

    // ---- f1 K-loop: 28 ksteps, pipelined, barrier-free ----
    f32x16 ac0 = zero16(), ac1 = zero16(), ac2 = zero16();
    {
        const int ks0 = w * 28;
        uint4 M = ldM4(ks0);
        uint2 e0 = ldE(M.x & 0xffffu), e1 = ldE(M.x >> 16), e2 = ldE(M.y);
        uint2 e3 = ldE(M.z & 0xffffu), e4 = ldE(M.z >> 16), e5 = ldE(M.w);
        uint4 Mc = ldM4(ks0 + 1);
        const short* Wp16 = (const short*)Wp;
        for (int ks = ks0; ks < ks0 + 28; ++ks) {
            const short* ap = Wp16 + (size_t)ks * 1536 + lane * 8;
            bf16x8 A0 = *(const bf16x8*)(ap);
            bf16x8 A1 = *(const bf16x8*)(ap + 512);
            bf16x8 A2 = *(const bf16x8*)(ap + 1024);
            uint2 f0 = ldE(Mc.x & 0xffffu), f1v = ldE(Mc.x >> 16), f2v = ldE(Mc.y);
            uint2 f3 = ldE(Mc.z & 0xffffu), f4v = ldE(Mc.z >> 16), f5v = ldE(Mc.w);
            uint4 Mn = ldM4(ks + 2);
            unsigned g0, g1, g2, g3;
            fbuild(e0, e1, e2, g0, g1);
            fbuild(e3, e4, e5, g2, g3);
            bf16x8 bfr = asbf(make_uint4(g0, g1, g2, g3));
            ac0 = __builtin_amdgcn_mfma_f32_32x32x16_bf16(A0, bfr, ac0, 0, 0, 0);
            ac1 = __builtin_amdgcn_mfma_f32_32x32x16_bf16(A1, bfr, ac1, 0, 0, 0);
            ac2 = __builtin_amdgcn_mfma_f32_32x32x16_bf16(A2, bfr, ac2, 0, 0, 0);
            e0 = f0; e1 = f1v; e2 = f2v; e3 = f3; e4 = f4v; e5 = f5v; Mc = Mn;
        }
    }

    // ---- f1 K-reduction (C/D: row=(reg&3)+8*(reg>>2)+4*kha, col=lane&31) ----
    __syncthreads();
    float* Sum = (float*)(ldsb + SUM_OFF);   // [192][32]
    auto dump = [&](f32x16 a, int baserow, bool add) {
#pragma unroll
        for (int reg = 0; reg < 16; ++reg) {
            int row = baserow + (reg & 3) + 8 * (reg >> 2) + 4 * kha;
            int idx = row * 32 + col;
            if (add) Sum[idx] += a[reg]; else Sum[idx] = a[reg];
        }
    };
    for (int ph = 0; ph < 4; ++ph) {
        if (w == ph) {
            bool add = (ph != 0);
            dump(ac0, 0, add); dump(ac1, 32, add); dump(ac2, 64, add);
        }
        __syncthreads();
    }

    // ---- f2 (E region still intact; acc registers reused) ----
    f32x16 bc0 = zero16(), bc1 = zero16(), bc2 = zero16();
    {
        const short* W216 = (const short*)W2p;
        for (int t = 0; t < 3; ++t) {
            int ks2 = w * 3 + t;
            const short* ap = W216 + (size_t)ks2 * 1536 + lane * 8;
            bf16x8 A0 = *(const bf16x8*)(ap);
            bf16x8 A1 = *(const bf16x8*)(ap + 512);
            bf16x8 A2 = *(const bf16x8*)(ap + 1024);
            unsigned g[4];
#pragma unroll
            for (int j = 0; j < 2; ++j) {
                int m = ks2 * 4 + kha * 2 + j;
                int mc = m < 41 ? m : 40;
                uint2 ue = *(const uint2*)(ldsb + mc * ESTR + col * 8);
                unsigned lo = (ue.x & 0xffffu) | (ue.y << 16);
                unsigned hi = (ue.x >> 16) | (ue.y & 0xffff0000u);
                if (m >= 41) { lo = 0u; hi = 0u; }
                g[j * 2] = lo; g[j * 2 + 1] = hi;
            }
            bf16x8 bfr = asbf(make_uint4(g[0], g[1], g[2], g[3]));
            bc0 = __builtin_amdgcn_mfma_f32_32x32x16_bf16(A0, bfr, bc0, 0, 0, 0);
            bc1 = __builtin_amdgcn_mfma_f32_32x32x16_bf16(A1, bfr, bc1, 0, 0, 0);
            bc2 = __builtin_amdgcn_mfma_f32_32x32x16_bf16(A2, bfr, bc2, 0, 0, 0);
        }
    }
    __syncthreads();
    for (int ph = 0; ph < 4; ++ph) {
        if (w == ph) {
            bool add = (ph != 0);
            dump(bc0, 96, add); dump(bc1, 128, add); dump(bc2, 160, add);
        }
        __syncthreads();
    }

    // ---- epilogue: wave 0, lanes 0..31 ----
    if (w == 0 && lane < NCOL) {
        int c = lane;
        float pr0 = Sum[80 * 32 + c], pi0 = Sum[81 * 32 + c];
        float pr1 = Sum[82 * 32 + c], pi1 = Sum[83 * 32 + c];
        float t0 = 0.f, t1 = 0.f, t2 = 0.f, t3 = 0.f;
#pragma unroll
        for (int o = 0; o < 10; ++o) {
            float b2r = b2[o * 2], b2i = b2[o * 2 + 1];
            float b1r = b1[o * 2], b1i = b1[o * 2 + 1];
            int rb = o * 4;
            float B0r = Sum[(96 + rb + 0) * 32 + c] + b2r;
            float B0i = Sum[(96 + rb + 1) * 32 + c] + b2i;
            float B1r = Sum[(96 + rb + 2) * 32 + c] + b2r;
            float B1i = Sum[(96 + rb + 3) * 32 + c] + b2i;
            float A0r = Sum[(rb + 0) * 32 + c] + b1r;
            float A0i = Sum[(rb + 1) * 32 + c] + b1i;
            float A1r = Sum[(rb + 2) * 32 + c] + b1r;
            float A1i = Sum[(rb + 3) * 32 + c] + b1i;
            // A*B*conj(B) + conj(A)*B*B = 2*Re(A*conj(B)) * B
            float g0 = 2.f * (A0r * B0r + A0i * B0i);
            t0 += g0 * B0r; t1 += g0 * B0i;
            float g1 = 2.f * (A1r * B1r + A1i * B1i);
            t2 += g1 * B1r; t3 += g1 * B1i;
        }
        int b = b0 + c;
        if (b < B) {
            float dbm = task[(size_t)b * 4];
            float P   = exp2f(dbm * 0.33219280948873623f) * 0.5f;  // 10^(dbm/10)/2
            float kP2 = 3.1622776601683794e-05f * P * P;           // 1e-4/sqrt(10)*P^2
            float4 Ec = ((const float4*)x)[(size_t)b * 41 + 20];   // fp32 center
            float4 o4;
            o4.x = Ec.x + P * pr0 + kP2 * t0;
            o4.y = Ec.y + P * pi0 + kP2 * t1;
            o4.z = Ec.z + P * pr1 + kP2 * t2;
            o4.w = Ec.w + P * pi1 + kP2 * t3;
            ((float4*)out)[b] = o4;
        }
    }
}

extern "C" void kernel_launch(void* const* d_in, const int* in_sizes, int n_in,
                              void* d_out, int out_size, void* d_ws, size_t ws_size,
                              hipStream_t stream) {
    const float* x     = (const float*)d_in[0];
    const float* task  = (const float*)d_in[1];
    const float* pbcC  = (const float*)d_in[2];
    const float* W1    = (const float*)d_in[3];
    const float* b1    = (const float*)d_in[4];
    const float* W2    = (const float*)d_in[5];
    const float* b2    = (const float*)d_in[6];
    const int*   m_idx = (const int*)d_in[7];
    const int*   n_idx = (const int*)d_in[8];
    float* out = (float*)d_out;

    int S = in_sizes[7];
    int B = in_sizes[0] / (41 * 2 * 2);

    char* ws = (char*)d_ws;
    unsigned short* Wp  = (unsigned short*)(ws + WP_OFF);
    unsigned short* W2p = (unsigned short*)(ws + W2P_OFF);

    int prep_n = KS1 * 3 * 64 * 2 + KS2 * 3 * 64 * 2;   // 47616
    prep_kernel<<<(prep_n + 255) / 256, 256, 0, stream>>>(W1, W2, pbcC, Wp, W2p, S);

    int grid = (B + NCOL - 1) / NCOL;
    eqsonn_kernel<<<grid, 256, 0, stream>>>(x, task, Wp, W2p, m_idx, n_idx,
                                            b1, b2, out, B, S);
}

// Round 11
// 98.085 us; speedup vs baseline: 1.0371x; 1.0371x over previous
//
#include <hip/hip_runtime.h>
#include <hip/hip_bf16.h>

typedef short bf16x8 __attribute__((ext_vector_type(8)));
typedef float f32x16 __attribute__((ext_vector_type(16)));

#define NCOL  32
#define KS1   112             // f1 k-steps (K=1792, 16 per step, 4 s per step)
#define KS2   12              // f2 k-steps (K=192)
#define ESTR  264             // E row stride bytes (32 cols * 8B + 8 pad)

#define WP_OFF   0            // short [112][3][64][8] = 344064 B
#define W2P_OFF  344064       // short [12][3][64][8]  = 36864 B

#define MET_OFF  10824        // E region 41*264 = 10824; meta uint2[464] = 3712
#define SUM_OFF  14544        // f32 [192][32] = 24576 (waves 0-3)
#define SUM2_OFF 39120        // f32 [192][32] = 24576 (waves 4-7)
#define LDS_BYTES 63696

__device__ __forceinline__ unsigned short f2bf(float f) {
    union { float f; unsigned u; } v; v.f = f;
    unsigned r = v.u + 0x7FFFu + ((v.u >> 16) & 1u);
    return (unsigned short)(r >> 16);
}
__device__ __forceinline__ float bfl(unsigned u) {
    union { unsigned q; float f; } v; v.q = u << 16; return v.f;
}
__device__ __forceinline__ float bfh(unsigned u) {
    union { unsigned q; float f; } v; v.q = u & 0xffff0000u; return v.f;
}
__device__ __forceinline__ unsigned pk2(float a, float b) {
    __hip_bfloat162 h = __float22bfloat162_rn(make_float2(a, b));
    unsigned u; __builtin_memcpy(&u, &h, 4); return u;
}
__device__ __forceinline__ bf16x8 asbf(uint4 v) {
    union { uint4 u; bf16x8 b; } z; z.u = v; return z.b;
}
__device__ __forceinline__ f32x16 zero16() {
    f32x16 z;
#pragma unroll
    for (int i = 0; i < 16; ++i) z[i] = 0.f;
    return z;
}

// prep (validated r10): A-frag layout for mfma_32x32x16.
// Wp[ks][mt][lane][8 shorts]; row = mt*32 + (lane&31); k = ks*16+(lane>>5)*8+v.
// Row r = o*4+p*2+reim (rows 80-83 = pbc C, 84-95 zero).
// k -> s=k>>2, t=k&3 (i=t&1 pol, cc=t>>1 re/im), plane j=i^p.
__global__ void prep_kernel(const float* __restrict__ W1,
                            const float* __restrict__ W2,
                            const float* __restrict__ pbcC,
                            unsigned short* __restrict__ Wp,
                            unsigned short* __restrict__ W2p, int S) {
    int idx = blockIdx.x * 256 + threadIdx.x;
    const int N1 = KS1 * 3 * 64 * 2;   // 43008
    const int N2 = KS2 * 3 * 64 * 2;   // 4608
    if (idx < N1) {
        int ks = idx / 384, rem = idx - ks * 384;
        int mt = rem >> 7; rem &= 127;
        int lane = rem >> 1, jh = rem & 1;
        int row = mt * 32 + (lane & 31);
        int kg  = ks * 16 + (lane >> 5) * 8 + jh * 4;
        int s   = kg >> 2;
        float2 wj0 = make_float2(0.f, 0.f), wj1 = make_float2(0.f, 0.f);
        int p = 0, r = 0;
        if (s < S) {
            if (row < 80) {
                int o = row >> 2; p = (row >> 1) & 1; r = row & 1;
                wj0 = ((const float2*)W1)[(size_t)(o * 2 + 0) * S + s];
                wj1 = ((const float2*)W1)[(size_t)(o * 2 + 1) * S + s];
            } else if (row < 84) {
                p = (row >> 1) & 1; r = row & 1;
                wj0 = ((const float2*)pbcC)[s];
            }
        }
        ushort4 h; unsigned short us[4];
#pragma unroll
        for (int t = 0; t < 4; ++t) {
            int i = t & 1, cc = t >> 1, j2 = i ^ p;
            float2 w = j2 ? wj1 : wj0;
            float v = (cc == 0) ? (r ? w.y : w.x) : (r ? w.x : -w.y);
            us[t] = f2bf(v);
        }
        h.x = us[0]; h.y = us[1]; h.z = us[2]; h.w = us[3];
        ((ushort4*)Wp)[idx] = h;
        return;
    }
    idx -= N1;
    if (idx < N2) {
        int ks = idx / 384, rem = idx - ks * 384;
        int mt = rem >> 7; rem &= 127;
        int lane = rem >> 1, jh = rem & 1;
        int row = mt * 32 + (lane & 31);
        int kg  = ks * 16 + (lane >> 5) * 8 + jh * 4;
        int m   = kg >> 2;
        float2 wj0 = make_float2(0.f, 0.f), wj1 = make_float2(0.f, 0.f);
        int p = 0, r = 0;
        if (m < 41 && row < 80) {
            int o = row >> 2; p = (row >> 1) & 1; r = row & 1;
            wj0 = ((const float2*)W2)[(o * 2 + 0) * 41 + m];
            wj1 = ((const float2*)W2)[(o * 2 + 1) * 41 + m];
        }
        ushort4 h; unsigned short us[4];
#pragma unroll
        for (int t = 0; t < 4; ++t) {
            int i = t & 1, cc = t >> 1, j2 = i ^ p;
            float2 w = j2 ? wj1 : wj0;
            float v = (cc == 0) ? (r ? w.y : w.x) : (r ? w.x : -w.y);
            us[t] = f2bf(v);
        }
        h.x = us[0]; h.y = us[1]; h.z = us[2]; h.w = us[3];
        ((ushort4*)W2p)[idx] = h;
    }
}

// 512-thr blocks: 32 cols, 8 waves = K-eighths (14 ks each) -> 4 waves/SIMD.
// Pipelined barrier-free K-loop (meta 2 ahead, E 1 ahead, A-frag 1 ks ahead).
__global__ __launch_bounds__(512, 4) void eqsonn_kernel(
    const float* __restrict__ x, const float* __restrict__ task,
    const unsigned short* __restrict__ Wp,  // short [112][3][64][8]
    const unsigned short* __restrict__ W2p, // short [12][3][64][8]
    const int* __restrict__ m_idx, const int* __restrict__ n_idx,
    const float* __restrict__ b1, const float* __restrict__ b2,
    float* __restrict__ out, int B, int S)
{
    __shared__ alignas(16) char ldsb[LDS_BYTES];
    const int tid  = threadIdx.x;
    const int lane = tid & 63;
    const int w    = __builtin_amdgcn_readfirstlane(tid >> 6);   // 0..7
    const int col  = lane & 31;
    const int kha  = lane >> 5;
    const int b0   = blockIdx.x * NCOL;

    // ---- stage E bf16: row k at k*264 + col*8 ----
    for (int e = tid; e < 41 * NCOL; e += 512) {
        int bb = e / 41, k = e - bb * 41;
        int bs = b0 + bb; if (bs > B - 1) bs = B - 1;
        float4 v = ((const float4*)x)[(size_t)bs * 41 + k];
        ushort4 h;
        h.x = f2bf(v.x); h.y = f2bf(v.y); h.z = f2bf(v.z); h.w = f2bf(v.w);
        *(ushort4*)(ldsb + k * ESTR + bb * 8) = h;
    }
    // ---- stage meta byte-offsets, zero-padded to 464 ----
    if (tid < 464) {
        int m = 0, n = 0;
        if (tid < S) { m = m_idx[tid]; n = n_idx[tid]; }
        unsigned offM = (unsigned)((20 + m) * ESTR);
        unsigned offB = (unsigned)((20 + m + n) * ESTR);
        unsigned offN = (unsigned)((20 + n) * ESTR);
        *(uint2*)(ldsb + MET_OFF + tid * 8) = make_uint2(offM | (offB << 16), offN);
    }
    __syncthreads();

    const char* Ebase = ldsb + col * 8;
    auto ldM4 = [&](int ks) -> uint4 {
        return *(const uint4*)(ldsb + MET_OFF + (ks * 4 + kha * 2) * 8);
    };
    auto ldE = [&](unsigned off) -> uint2 {
        return *(const uint2*)(Ebase + off);
    };
    auto fbuild = [&](uint2 em, uint2 eq, uint2 en, unsigned& lo, unsigned& hi) {
        float m0r = bfl(em.x), m0i = bfh(em.x), m1r = bfl(em.y), m1i = bfh(em.y);
        float q0r = bfl(eq.x), q0i = bfh(eq.x), q1r = bfl(eq.y), q1i = bfh(eq.y);
        float n0r = bfl(en.x), n0i = bfh(en.x), n1r = bfl(en.y), n1i = bfh(en.y);
        float sr = m0r * q0r + m0i * q0i + m1r * q1r + m1i * q1i;
        float si = m0i * q0r - m0r * q0i + m1i * q1r - m1r * q1i;
        float F0r = sr * n0r - si * n0i, F0i = sr * n0i + si * n0r;
        float F1r = sr * n1r - si * n1i, F1i = sr * n1i + si * n1r;
        lo = pk2(F0r, F1r); hi = pk2(F0i, F1i);
    };

    // ---- f1 K-loop: 14 ksteps/wave, pipelined, barrier-free ----
    f32x16 ac0 = zero16(), ac1 = zero16(), ac2 = zero16();
    {
        const int ks0 = w * 14;
        const short* Wp16 = (const short*)Wp;
        uint4 M = ldM4(ks0);
        uint2 e0 = ldE(M.x & 0xffffu), e1 = ldE(M.x >> 16), e2 = ldE(M.y);
        uint2 e3 = ldE(M.z & 0xffffu), e4 = ldE(M.z >> 16), e5 = ldE(M.w);
        uint4 Mc = ldM4(ks0 + 1);
        const short* ap0 = Wp16 + (size_t)ks0 * 1536 + lane * 8;
        bf16x8 A0 = *(const bf16x8*)(ap0);
        bf16x8 A1 = *(const bf16x8*)(ap0 + 512);
        bf16x8 A2 = *(const bf16x8*)(ap0 + 1024);
        for (int ks = ks0; ks < ks0 + 14; ++ks) {
            // prefetch next A-frags (wave-uniform clamp)
            int ksn = (ks + 1 < KS1) ? ks + 1 : KS1 - 1;
            const short* apn = Wp16 + (size_t)ksn * 1536 + lane * 8;
            bf16x8 N0 = *(const bf16x8*)(apn);
            bf16x8 N1 = *(const bf16x8*)(apn + 512);
            bf16x8 N2 = *(const bf16x8*)(apn + 1024);
            // prefetch next E values + meta 2 ahead
            uint2 f0 = ldE(Mc.x & 0xffffu), f1v = ldE(Mc.x >> 16), f2v = ldE(Mc.y);
            uint2 f3 = ldE(Mc.z & 0xffffu), f4v = ldE(Mc.z >> 16), f5v = ldE(Mc.w);
            uint4 Mn = ldM4(ks + 2);
            unsigned g0, g1, g2, g3;
            fbuild(e0, e1, e2, g0, g1);
            fbuild(e3, e4, e5, g2, g3);
            bf16x8 bfr = asbf(make_uint4(g0, g1, g2, g3));
            ac0 = __builtin_amdgcn_mfma_f32_32x32x16_bf16(A0, bfr, ac0, 0, 0, 0);
            ac1 = __builtin_amdgcn_mfma_f32_32x32x16_bf16(A1, bfr, ac1, 0, 0, 0);
            ac2 = __builtin_amdgcn_mfma_f32_32x32x16_bf16(A2, bfr, ac2, 0, 0, 0);
            e0 = f0; e1 = f1v; e2 = f2v; e3 = f3; e4 = f4v; e5 = f5v; Mc = Mn;
            A0 = N0; A1 = N1; A2 = N2;
        }
    }

    // ---- f1 reduction: waves 0-3 -> Sum, waves 4-7 -> Sum2 (4 phases) ----
    __syncthreads();
    float* Reg = (float*)(ldsb + ((w < 4) ? SUM_OFF : SUM2_OFF));
    const int ph = w & 3;
    auto dump = [&](f32x16 a, int baserow, bool add) {
#pragma unroll
        for (int reg = 0; reg < 16; ++reg) {
            int row = baserow + (reg & 3) + 8 * (reg >> 2) + 4 * kha;
            int idx = row * 32 + col;
            if (add) Reg[idx] += a[reg]; else Reg[idx] = a[reg];
        }
    };
    for (int p = 0; p < 4; ++p) {
        if (ph == p) {
            bool add = (p != 0);
            dump(ac0, 0, add); dump(ac1, 32, add); dump(ac2, 64, add);
        }
        __syncthreads();
    }

    // ---- f2 (E region intact; acc regs reused): wave w -> ks2 {w, w+8(w<4)} ----
    f32x16 bc0 = zero16(), bc1 = zero16(), bc2 = zero16();
    {
        const short* W216 = (const short*)W2p;
        for (int ks2 = w; ks2 < KS2; ks2 += 8) {
            const short* ap = W216 + (size_t)ks2 * 1536 + lane * 8;
            bf16x8 A0 = *(const bf16x8*)(ap);
            bf16x8 A1 = *(const bf16x8*)(ap + 512);
            bf16x8 A2 = *(const bf16x8*)(ap + 1024);
            unsigned g[4];
#pragma unroll
            for (int j = 0; j < 2; ++j) {
                int m = ks2 * 4 + kha * 2 + j;
                int mc = m < 41 ? m : 40;
                uint2 ue = *(const uint2*)(ldsb + mc * ESTR + col * 8);
                unsigned lo = (ue.x & 0xffffu) | (ue.y << 16);
                unsigned hi = (ue.x >> 16) | (ue.y & 0xffff0000u);
                if (m >= 41) { lo = 0u; hi = 0u; }
                g[j * 2] = lo; g[j * 2 + 1] = hi;
            }
            bf16x8 bfr = asbf(make_uint4(g[0], g[1], g[2], g[3]));
            bc0 = __builtin_amdgcn_mfma_f32_32x32x16_bf16(A0, bfr, bc0, 0, 0, 0);
            bc1 = __builtin_amdgcn_mfma_f32_32x32x16_bf16(A1, bfr, bc1, 0, 0, 0);
            bc2 = __builtin_amdgcn_mfma_f32_32x32x16_bf16(A2, bfr, bc2, 0, 0, 0);
        }
    }
    __syncthreads();
    for (int p = 0; p < 4; ++p) {
        if (ph == p) {
            bool add = (p != 0);
            dump(bc0, 96, add); dump(bc1, 128, add); dump(bc2, 160, add);
        }
        __syncthreads();
    }

    // ---- merge Sum += Sum2 (vectorized, all 512 threads) ----
    {
        float4* S1 = (float4*)(ldsb + SUM_OFF);
        float4* S2 = (float4*)(ldsb + SUM2_OFF);
#pragma unroll
        for (int i = 0; i < 3; ++i) {
            int idx = tid + i * 512;   // 1536 float4 total
            float4 a = S1[idx], b = S2[idx];
            a.x += b.x; a.y += b.y; a.z += b.z; a.w += b.w;
            S1[idx] = a;
        }
    }
    __syncthreads();

    // ---- epilogue: wave 0, lanes 0..31 ----
    if (w == 0 && lane < NCOL) {
        const float* Sum = (const float*)(ldsb + SUM_OFF);
        int c = lane;
        float pr0 = Sum[80 * 32 + c], pi0 = Sum[81 * 32 + c];
        float pr1 = Sum[82 * 32 + c], pi1 = Sum[83 * 32 + c];
        float t0 = 0.f, t1 = 0.f, t2 = 0.f, t3 = 0.f;
#pragma unroll
        for (int o = 0; o < 10; ++o) {
            float b2r = b2[o * 2], b2i = b2[o * 2 + 1];
            float b1r = b1[o * 2], b1i = b1[o * 2 + 1];
            int rb = o * 4;
            float B0r = Sum[(96 + rb + 0) * 32 + c] + b2r;
            float B0i = Sum[(96 + rb + 1) * 32 + c] + b2i;
            float B1r = Sum[(96 + rb + 2) * 32 + c] + b2r;
            float B1i = Sum[(96 + rb + 3) * 32 + c] + b2i;
            float A0r = Sum[(rb + 0) * 32 + c] + b1r;
            float A0i = Sum[(rb + 1) * 32 + c] + b1i;
            float A1r = Sum[(rb + 2) * 32 + c] + b1r;
            float A1i = Sum[(rb + 3) * 32 + c] + b1i;
            // A*B*conj(B) + conj(A)*B*B = 2*Re(A*conj(B)) * B
            float g0 = 2.f * (A0r * B0r + A0i * B0i);
            t0 += g0 * B0r; t1 += g0 * B0i;
            float g1 = 2.f * (A1r * B1r + A1i * B1i);
            t2 += g1 * B1r; t3 += g1 * B1i;
        }
        int b = b0 + c;
        if (b < B) {
            float dbm = task[(size_t)b * 4];
            float P   = exp2f(dbm * 0.33219280948873623f) * 0.5f;  // 10^(dbm/10)/2
            float kP2 = 3.1622776601683794e-05f * P * P;           // 1e-4/sqrt(10)*P^2
            float4 Ec = ((const float4*)x)[(size_t)b * 41 + 20];   // fp32 center
            float4 o4;
            o4.x = Ec.x + P * pr0 + kP2 * t0;
            o4.y = Ec.y + P * pi0 + kP2 * t1;
            o4.z = Ec.z + P * pr1 + kP2 * t2;
            o4.w = Ec.w + P * pi1 + kP2 * t3;
            ((float4*)out)[b] = o4;
        }
    }
}

extern "C" void kernel_launch(void* const* d_in, const int* in_sizes, int n_in,
                              void* d_out, int out_size, void* d_ws, size_t ws_size,
                              hipStream_t stream) {
    const float* x     = (const float*)d_in[0];
    const float* task  = (const float*)d_in[1];
    const float* pbcC  = (const float*)d_in[2];
    const float* W1    = (const float*)d_in[3];
    const float* b1    = (const float*)d_in[4];
    const float* W2    = (const float*)d_in[5];
    const float* b2    = (const float*)d_in[6];
    const int*   m_idx = (const int*)d_in[7];
    const int*   n_idx = (const int*)d_in[8];
    float* out = (float*)d_out;

    int S = in_sizes[7];
    int B = in_sizes[0] / (41 * 2 * 2);

    char* ws = (char*)d_ws;
    unsigned short* Wp  = (unsigned short*)(ws + WP_OFF);
    unsigned short* W2p = (unsigned short*)(ws + W2P_OFF);

    int prep_n = KS1 * 3 * 64 * 2 + KS2 * 3 * 64 * 2;   // 47616
    prep_kernel<<<(prep_n + 255) / 256, 256, 0, stream>>>(W1, W2, pbcC, Wp, W2p, S);

    int grid = (B + NCOL - 1) / NCOL;
    eqsonn_kernel<<<grid, 512, 0, stream>>>(x, task, Wp, W2p, m_idx, n_idx,
                                            b1, b2, out, B, S);
}